// Round 7
// baseline (249.026 us; speedup 1.0000x reference)
//
#include <hip/hip_runtime.h>

// Fused Damping v7: B=32768, N=64, H=256, OFF=2016.
// = v4 (verified numerics: unpack + fp32 fma V/OUT, fp32 x) plus:
//   - s8tab LUT in LDS (no per-access s8idx recompute)
//   - OUT staged in LDS, coalesced float4 store (fixes WRITE_SIZE blowup)
//   - pack kernel back to one-thread-per-octet (wave-coalesced reads)
// dot2 path from v5/v6 abandoned: error invariant to rounding mode ->
// v_dot2_f32_bf16 numeric behavior on gfx950 differs from assumption.

#define BT 16
#define THREADS 512

typedef short short8 __attribute__((ext_vector_type(8)));
typedef float floatx4 __attribute__((ext_vector_type(4)));

__device__ __forceinline__ ushort f2bf(float f) {
    uint u = __builtin_bit_cast(uint, f);
    u += 0x7FFFu + ((u >> 16) & 1u);
    return (ushort)(u >> 16);
}
__device__ __forceinline__ uint pk2bf(float lo, float hi) {
    uint a = __builtin_bit_cast(uint, lo);
    a += 0x7FFFu + ((a >> 16) & 1u);
    uint b = __builtin_bit_cast(uint, hi);
    b += 0x7FFFu + ((b >> 16) & 1u);
    return (a >> 16) | (b & 0xFFFF0000u);
}
__device__ __forceinline__ float bf2f(ushort h) {
    return __builtin_bit_cast(float, ((uint)h) << 16);
}
__device__ __forceinline__ float bflo(uint u) { return __builtin_bit_cast(float, u << 16); }
__device__ __forceinline__ float bfhi(uint u) { return __builtin_bit_cast(float, u & 0xFFFF0000u); }
__device__ __forceinline__ float fast_tanh(float x) {
    return 1.f - 2.f / (__expf(2.f * x) + 1.f);
}
// start (in ushorts) of 8-padded triangle row k
__device__ __forceinline__ int s8idx(int k) {
    int a = k >> 3, r = k & 7;
    return 8 * (r ? (a + 1) * (4 * a + r - 1) : a * (4 * a + 3));
}

// ---- pack: one thread per OCTET (consecutive lanes -> consecutive cols,
// wave-coalesced global reads; one 16B packed store per thread) ----
// Octet ranges: wd1[0,2048) wo1[2048,4096) wd2[4096,12288) wo2[12288,20480)
// wdo[20480,22528) woo[22528,94208). gids [94208, 96448): boo_p8.
__global__ void pack_all(const float* __restrict__ Wd1, const float* __restrict__ Wd2,
                         const float* __restrict__ Wdo, const float* __restrict__ Wo1,
                         const float* __restrict__ Wo2, const float* __restrict__ Woo,
                         const float* __restrict__ boo,
                         ushort* __restrict__ ws, float* __restrict__ boo_p8) {
    int gid = blockIdx.x * blockDim.x + threadIdx.x;
    if (gid >= 94208) {
        int p = gid - 94208;
        if (p < 2240) {
            int kr = (int)sqrtf(2.f * (float)p);
            if (kr < 1) kr = 1;
            if (kr > 63) kr = 63;
            while (kr < 63 && s8idx(kr + 1) <= p) kr++;
            while (kr > 1 && s8idx(kr) > p) kr--;
            int jj = p - s8idx(kr);
            boo_p8[p] = (jj < kr) ? boo[kr * (kr - 1) / 2 + jj] : 0.f;
        }
        return;
    }
    int oct = gid;
    const float* W; int base, Ncols, KT, woo;
    if (oct < 2048)       { W = Wd1; base = 0;     Ncols = 256;  KT = 2; woo = 0; }
    else if (oct < 4096)  { W = Wo1; base = 2048;  Ncols = 256;  KT = 2; woo = 0; }
    else if (oct < 12288) { W = Wd2; base = 4096;  Ncols = 256;  KT = 8; woo = 0; }
    else if (oct < 20480) { W = Wo2; base = 12288; Ncols = 256;  KT = 8; woo = 0; }
    else if (oct < 22528) { W = Wdo; base = 20480; Ncols = 64;   KT = 8; woo = 0; }
    else                  { W = Woo; base = 22528; Ncols = 2016; KT = 8; woo = 1; }
    int lg = oct - base;
    int lane = lg & 63;
    int kt = (lg >> 6) % KT;
    int tile = lg / (64 * KT);
    int q = lane >> 4, ni = lane & 15;
    int col = tile * 16 + ni;            // out-col (std) or padded p8 index (Woo)
    int valid = 1;
    if (woo) {
        int p = col;
        int kr = (int)sqrtf(2.f * (float)p);
        if (kr < 1) kr = 1;
        if (kr > 63) kr = 63;
        while (kr < 63 && s8idx(kr + 1) <= p) kr++;
        while (kr > 1 && s8idx(kr) > p) kr--;
        int jj = p - s8idx(kr);
        valid = (jj < kr);
        col = valid ? (kr * (kr - 1) / 2 + jj) : 0;
    }
    short8 v8;
#pragma unroll
    for (int j = 0; j < 8; j++) {
        int k = kt * 32 + q * 8 + j;
        float val = valid ? W[(size_t)k * Ncols + col] : 0.f;
        v8[j] = (short)f2bf(val);
    }
    *(short8*)(ws + (size_t)oct * 8) = v8;
}

// ---- LDS layout (bytes), total 80,896 -> 2 WGs/CU (161,792 <= 163,840) ----
// off8 [16][2248] us @ 0 (71,936); overlays inside (dead before off8 write):
//   xbf@0 [16][88]us; act_d@4096 act_o@12544 act_d2@20992 act_o2@29440
// xs   [16][64] f32 @ 71,936 (4,096)   x fp32; reused as OUT staging after V
// dgb  [16][72] bf16 @ 76,032 (2,304)
// vb   [16][72] bf16 @ 78,336 (2,304)
// s8tab 64 ints      @ 80,640 (256)
#define BSTR8 2248
#define XBF_STR 88
#define ASTR 264
#define DGSTR 72
#define ACT_D  4096
#define ACT_O  12544
#define ACT_D2 20992
#define ACT_O2 29440
#define XS_B   71936
#define DG_B   76032
#define VB_B   78336
#define S8_B   80640
#define LDS_BYTES 80896

#define FRAGW(p, idx) (*(const short8*)((p) + (size_t)(idx) * 512 + (size_t)lane * 8))

__global__ __launch_bounds__(THREADS, 4)
void damping_fused(const float* __restrict__ x,
                   const ushort* __restrict__ wd1f, const ushort* __restrict__ wd2f,
                   const ushort* __restrict__ wdof, const ushort* __restrict__ wo1f,
                   const ushort* __restrict__ wo2f, const ushort* __restrict__ woof,
                   const float* __restrict__ bd1, const float* __restrict__ bd2,
                   const float* __restrict__ bdo, const float* __restrict__ bo1,
                   const float* __restrict__ bo2, const float* __restrict__ boo_p8,
                   const float* __restrict__ dmin, float* __restrict__ out) {
    extern __shared__ char smem[];
    ushort* off8   = (ushort*)smem;
    ushort* xbf    = (ushort*)smem;
    ushort* act_d  = (ushort*)(smem + ACT_D);
    ushort* act_o  = (ushort*)(smem + ACT_O);
    ushort* act_d2 = (ushort*)(smem + ACT_D2);
    ushort* act_o2 = (ushort*)(smem + ACT_O2);
    float*  xs     = (float*)(smem + XS_B);   // x fp32; OUT staging after V
    ushort* dgb    = (ushort*)(smem + DG_B);
    ushort* vb     = (ushort*)(smem + VB_B);
    int*    s8tab  = (int*)(smem + S8_B);

    const int tid  = threadIdx.x;
    const int lane = tid & 63;
    const int w    = tid >> 6;
    const int q    = lane >> 4;
    const int ni   = lane & 15;
    const int b0   = blockIdx.x * BT;

    // ---- P1: load x [16][64] fp32 + bf16 mirror + s8 LUT ----
    if (tid < 256) {
        int row = tid >> 4;
        int c = (tid & 15) * 4;
        const float4 xv = *(const float4*)(x + (size_t)(b0 + row) * 64 + c);
        float* xr = xs + row * 64 + c;
        xr[0] = xv.x; xr[1] = xv.y; xr[2] = xv.z; xr[3] = xv.w;
        uint2 p;
        p.x = pk2bf(xv.x, xv.y);
        p.y = pk2bf(xv.z, xv.w);
        *(uint2*)(xbf + row * XBF_STR + c) = p;
    }
    if (tid >= 448) {
        int k = tid - 448;
        s8tab[k] = s8idx(k);
    }
    __syncthreads();

    const int br = w >> 2;           // 0: diag branch, 1: off branch

    // ---- P2: layer1 (K=64) ----
    {
        const ushort* wf = br ? wo1f : wd1f;
        const float*  bs = br ? bo1 : bd1;
        ushort* aout = br ? act_o : act_d;
        floatx4 acc[4] = {};
        for (int kt = 0; kt < 2; kt++) {
            short8 bfrg = *(const short8*)(xbf + ni * XBF_STR + kt * 32 + q * 8);
#pragma unroll
            for (int tt = 0; tt < 4; tt++) {
                short8 af = FRAGW(wf, ((w & 3) * 4 + tt) * 2 + kt);
                acc[tt] = __builtin_amdgcn_mfma_f32_16x16x32_bf16(af, bfrg, acc[tt], 0, 0, 0);
            }
        }
#pragma unroll
        for (int tt = 0; tt < 4; tt++) {
            int col0 = ((w & 3) * 4 + tt) * 16 + q * 4;
            float4 bias = *(const float4*)(bs + col0);
            uint2 p;
            p.x = pk2bf(fast_tanh(acc[tt][0] + bias.x), fast_tanh(acc[tt][1] + bias.y));
            p.y = pk2bf(fast_tanh(acc[tt][2] + bias.z), fast_tanh(acc[tt][3] + bias.w));
            *(uint2*)(aout + ni * ASTR + col0) = p;
        }
    }
    __syncthreads();

    // ---- P3: layer2 (K=256) ----
    {
        const ushort* wf = br ? wo2f : wd2f;
        const float*  bs = br ? bo2 : bd2;
        const ushort* ain = br ? act_o : act_d;
        ushort* aout = br ? act_o2 : act_d2;
        floatx4 acc[4] = {};
        for (int kt = 0; kt < 8; kt++) {
            short8 bfrg = *(const short8*)(ain + ni * ASTR + kt * 32 + q * 8);
#pragma unroll
            for (int tt = 0; tt < 4; tt++) {
                short8 af = FRAGW(wf, ((w & 3) * 4 + tt) * 8 + kt);
                acc[tt] = __builtin_amdgcn_mfma_f32_16x16x32_bf16(af, bfrg, acc[tt], 0, 0, 0);
            }
        }
#pragma unroll
        for (int tt = 0; tt < 4; tt++) {
            int col0 = ((w & 3) * 4 + tt) * 16 + q * 4;
            float4 bias = *(const float4*)(bs + col0);
            uint2 p;
            p.x = pk2bf(fast_tanh(acc[tt][0] + bias.x), fast_tanh(acc[tt][1] + bias.y));
            p.y = pk2bf(fast_tanh(acc[tt][2] + bias.z), fast_tanh(acc[tt][3] + bias.w));
            *(uint2*)(aout + ni * ASTR + col0) = p;
        }
    }
    __syncthreads();

    // ---- P4 (waves 0-3): diag layer3 -> dgb = bf16((relu(d)+dmin)*x) ----
    if (w < 4) {
        floatx4 acc = {};
        for (int kt = 0; kt < 8; kt++) {
            short8 bfrg = *(const short8*)(act_d2 + ni * ASTR + kt * 32 + q * 8);
            short8 af = FRAGW(wdof, w * 8 + kt);
            acc = __builtin_amdgcn_mfma_f32_16x16x32_bf16(af, bfrg, acc, 0, 0, 0);
        }
        int col0 = w * 16 + q * 4;
        float4 bias = *(const float4*)(bdo + col0);
        float4 dmv  = *(const float4*)(dmin + col0);
        float g0, g1, g2, g3;
        {
            float d;
            d = acc[0] + bias.x; g0 = ((d > 0.f) ? d : 0.f) + dmv.x;
            d = acc[1] + bias.y; g1 = ((d > 0.f) ? d : 0.f) + dmv.y;
            d = acc[2] + bias.z; g2 = ((d > 0.f) ? d : 0.f) + dmv.z;
            d = acc[3] + bias.w; g3 = ((d > 0.f) ? d : 0.f) + dmv.w;
        }
        g0 *= xs[ni * 64 + col0];
        g1 *= xs[ni * 64 + col0 + 1];
        g2 *= xs[ni * 64 + col0 + 2];
        g3 *= xs[ni * 64 + col0 + 3];
        uint2 p;
        p.x = pk2bf(g0, g1);
        p.y = pk2bf(g2, g3);
        *(uint2*)(dgb + ni * DGSTR + col0) = p;
    }

    // ---- P5: Woo GEMM (140 tiles; extras on waves 4-7 to balance P4) ----
    floatx4 oacc[17];
#pragma unroll
    for (int t = 0; t < 17; t++) oacc[t] = (floatx4){0.f, 0.f, 0.f, 0.f};
    floatx4 oaccx = {};
    for (int kt = 0; kt < 8; kt++) {
        short8 bfrg = *(const short8*)(act_o2 + ni * ASTR + kt * 32 + q * 8);
#pragma unroll
        for (int t = 0; t < 17; t++) {
            short8 af = FRAGW(woof, (size_t)(t * 8 + w) * 8 + kt);
            oacc[t] = __builtin_amdgcn_mfma_f32_16x16x32_bf16(af, bfrg, oacc[t], 0, 0, 0);
        }
        if (w >= 4) {
            short8 af = FRAGW(woof, (size_t)(136 + (w - 4)) * 8 + kt);
            oaccx = __builtin_amdgcn_mfma_f32_16x16x32_bf16(af, bfrg, oaccx, 0, 0, 0);
        }
    }
    __syncthreads();   // act reads done -> off8 region reusable

    // ---- P5e: write off8 (+bias) ----
#pragma unroll
    for (int t = 0; t < 17; t++) {
        int p0 = (t * 8 + w) * 16 + q * 4;
        float4 bias = *(const float4*)(boo_p8 + p0);
        uint2 pw;
        pw.x = pk2bf(oacc[t][0] + bias.x, oacc[t][1] + bias.y);
        pw.y = pk2bf(oacc[t][2] + bias.z, oacc[t][3] + bias.w);
        *(uint2*)(off8 + ni * BSTR8 + p0) = pw;
    }
    if (w >= 4) {
        int p0 = (136 + (w - 4)) * 16 + q * 4;
        float4 bias = *(const float4*)(boo_p8 + p0);
        uint2 pw;
        pw.x = pk2bf(oaccx[0] + bias.x, oaccx[1] + bias.y);
        pw.y = pk2bf(oaccx[2] + bias.z, oaccx[3] + bias.w);
        *(uint2*)(off8 + ni * BSTR8 + p0) = pw;
    }
    __syncthreads();

    // ---- V: v[j] = dg[j]*x[j] + sum_{k>j} off[k][j]*x[k]  (chunked b128) ----
    const int ko = lane >> 3, jb = lane & 7;
    for (int rr = 0; rr < 2; rr++) {
        int b = w * 2 + rr;
        const ushort* rowb = off8 + b * BSTR8;
        float s[8] = {0.f, 0.f, 0.f, 0.f, 0.f, 0.f, 0.f, 0.f};
#pragma unroll
        for (int kk = 0; kk < 8; kk++) {
            int k = kk * 8 + ko;
            uint4 u = *(const uint4*)(rowb + s8tab[k] + 8 * jb);
            float xk = xs[b * 64 + k];
            xk = (8 * jb < k) ? xk : 0.f;
            s[0] += bflo(u.x) * xk; s[1] += bfhi(u.x) * xk;
            s[2] += bflo(u.y) * xk; s[3] += bfhi(u.y) * xk;
            s[4] += bflo(u.z) * xk; s[5] += bfhi(u.z) * xk;
            s[6] += bflo(u.w) * xk; s[7] += bfhi(u.w) * xk;
        }
#pragma unroll
        for (int e = 0; e < 8; e++) {
            s[e] += __shfl_xor(s[e], 8);
            s[e] += __shfl_xor(s[e], 16);
            s[e] += __shfl_xor(s[e], 32);
        }
        if (lane < 8) {               // ko==0, jb==lane
            int j0 = lane * 8;
            uint4 d = *(const uint4*)(dgb + b * DGSTR + j0);
            float4 xa = *(const float4*)(xs + b * 64 + j0);
            float4 xc = *(const float4*)(xs + b * 64 + j0 + 4);
            s[0] += bflo(d.x) * xa.x; s[1] += bfhi(d.x) * xa.y;
            s[2] += bflo(d.y) * xa.z; s[3] += bfhi(d.y) * xa.w;
            s[4] += bflo(d.z) * xc.x; s[5] += bfhi(d.z) * xc.y;
            s[6] += bflo(d.w) * xc.z; s[7] += bfhi(d.w) * xc.w;
            uint4 o;
            o.x = pk2bf(s[0], s[1]); o.y = pk2bf(s[2], s[3]);
            o.z = pk2bf(s[4], s[5]); o.w = pk2bf(s[6], s[7]);
            *(uint4*)(vb + b * DGSTR + j0) = o;
        }
    }
    __syncthreads();

    // ---- OUT: out[i] = dg[i]*v[i] + sum_{j<i} off[i][j]*v[j] -> stage in LDS ----
    float* outs = xs;                 // xs dead after V -> reuse as out staging
    const int io = lane >> 3;
    for (int rr = 0; rr < 2; rr++) {
        int b = w * 2 + rr;
        const ushort* rowb = off8 + b * BSTR8;
        uint4 vv = *(const uint4*)(vb + b * DGSTR + 8 * jb);
        float v0 = bflo(vv.x), v1 = bfhi(vv.x), v2 = bflo(vv.y), v3 = bfhi(vv.y);
        float v4 = bflo(vv.z), v5 = bfhi(vv.z), v6 = bflo(vv.w), v7 = bfhi(vv.w);
#pragma unroll
        for (int ig = 0; ig < 8; ig++) {
            int i = ig * 8 + io;
            uint4 u = *(const uint4*)(rowb + s8tab[i] + 8 * jb);
            float t;
            t  = bflo(u.x) * v0; t += bfhi(u.x) * v1;
            t += bflo(u.y) * v2; t += bfhi(u.y) * v3;
            t += bflo(u.z) * v4; t += bfhi(u.z) * v5;
            t += bflo(u.w) * v6; t += bfhi(u.w) * v7;
            t = (8 * jb < i) ? t : 0.f;
            t += __shfl_xor(t, 1);
            t += __shfl_xor(t, 2);
            t += __shfl_xor(t, 4);
            if (jb == 0) {
                float dgi = bf2f(dgb[b * DGSTR + i]);
                float vi  = bf2f(vb[b * DGSTR + i]);
                outs[b * 64 + i] = t + dgi * vi;
            }
        }
    }
    __syncthreads();

    // ---- P7: coalesced float4 store ----
    if (tid < 256) {
        int row = tid >> 4, c = (tid & 15) * 4;
        *(float4*)(out + (size_t)(b0 + row) * 64 + c) = *(const float4*)(outs + row * 64 + c);
    }
}

extern "C" void kernel_launch(void* const* d_in, const int* in_sizes, int n_in,
                              void* d_out, int out_size, void* d_ws, size_t ws_size,
                              hipStream_t stream) {
    const float* x    = (const float*)d_in[0];
    const float* Wd1  = (const float*)d_in[1];
    const float* bd1  = (const float*)d_in[2];
    const float* Wd2  = (const float*)d_in[3];
    const float* bd2  = (const float*)d_in[4];
    const float* Wdo  = (const float*)d_in[5];
    const float* bdo  = (const float*)d_in[6];
    const float* Wo1  = (const float*)d_in[7];
    const float* bo1  = (const float*)d_in[8];
    const float* Wo2  = (const float*)d_in[9];
    const float* bo2  = (const float*)d_in[10];
    const float* Woo  = (const float*)d_in[11];
    const float* boo  = (const float*)d_in[12];
    const float* dmin = (const float*)d_in[13];
    float* out = (float*)d_out;

    // ws (ushorts): frags 94208 octets = 753,664 us + boo_p8 2240 f32
    ushort* ws   = (ushort*)d_ws;
    ushort* wd1f = ws;
    ushort* wo1f = ws + 2048 * 8;
    ushort* wd2f = ws + 4096 * 8;
    ushort* wo2f = ws + 12288 * 8;
    ushort* wdof = ws + 20480 * 8;
    ushort* woof = ws + 22528 * 8;
    float*  boo_p8 = (float*)(ws + 753664);

    pack_all<<<377, 256, 0, stream>>>(Wd1, Wd2, Wdo, Wo1, Wo2, Woo, boo, ws, boo_p8);

    hipFuncSetAttribute((const void*)damping_fused,
                        hipFuncAttributeMaxDynamicSharedMemorySize, LDS_BYTES);

    damping_fused<<<32768 / BT, THREADS, LDS_BYTES, stream>>>(
        x, wd1f, wd2f, wdof, wo1f, wo2f, woof,
        bd1, bd2, bdo, bo1, bo2, boo_p8, dmin, out);
}